// Round 16
// baseline (163.842 us; speedup 1.0000x reference)
//
#include <hip/hip_runtime.h>

#define TLEN 512
#define HD 128
#define VOC 50000

typedef float fvec4 __attribute__((ext_vector_type(4)));   // f32 MFMA accumulator
typedef int   ivec4 __attribute__((ext_vector_type(4)));   // 16B LDS read
typedef int   ivec8 __attribute__((ext_vector_type(8)));   // 32 fp8 = f8f6f4 operand

// ---------------- emb fp32 -> fp8 e4m3 (x16 scale) table ----------------
__global__ void emb_cvt8(const float* __restrict__ emb, int* __restrict__ out, int n4){
  int i = blockIdx.x * blockDim.x + threadIdx.x;
  if (i < n4){
    float4 v = *(const float4*)(emb + (size_t)i * 4);
    int p = __builtin_amdgcn_cvt_pk_fp8_f32(16.f * v.x, 16.f * v.y, 0, 0);
    p     = __builtin_amdgcn_cvt_pk_fp8_f32(16.f * v.z, 16.f * v.w, p, 1);
    out[i] = p;
  }
}

// ---------------- persistent bidirectional GRU scan: 8-wave x 1 col-tile ----------------
// r15 structure (161.6us) + VALU/chain trim bundle:
//  - rec MFS order aR -> aU -> aZ (z is consumed LAST in the h update, so its MFS
//    issues last; r's chain starts a slot earlier, eZv exp2 hides under y-chain)
//  - bu folded into aU's MFS C-input (CUv) -- drops a dependent VALU add
//  - loop-invariant fvec4 C-registers for the xp weave (no per-use splats)
// 256 blocks = 256 CUs (96KB LDS pin): 0..127 fwd, 128..255 bwd; 4 batches each
// at A-tile rows {0,4,8,12}; only lanes (l15&3)==0 ds_read their A-frag (rest 0).
// Per wave per step: [pred] 2 ds_read_b128 + 1 woven xp MFS + 3 rec MFS + 1 gate
// + 1-byte h write + 1 barrier. All fp8 stored x16, e8m0 scale 2^-4/side (net 1).
// h master kept as 16*h (exact). r13 lesson: keep the 4-lanes/dword byte writes.
__global__ __launch_bounds__(512, 2) void gru_scan(
    const int* __restrict__ tokens, const unsigned char* __restrict__ embq,
    const float* __restrict__ Wf, const float* __restrict__ Uf, const float* __restrict__ bfv,
    const float* __restrict__ Wb, const float* __restrict__ Ub, const float* __restrict__ bbv,
    float* __restrict__ hbuf)
{
  const int tid  = threadIdx.x;
  const int wid  = tid >> 6, lane = tid & 63;
  const int l15  = lane & 15, l4 = lane >> 4;
  const int dir  = blockIdx.x >> 7, grp = blockIdx.x & 127;
  const int c    = wid * 16 + l15;                   // this lane's single gate column
  const bool rdr = (l15 & 3) == 0;                   // lane supplies a nonzero A row

  const float* __restrict__ W  = dir ? Wb : Wf;
  const float* __restrict__ U  = dir ? Ub : Uf;
  const float* __restrict__ bv = dir ? bbv : bfv;

  // claim 96KB -> 1 block/CU; used: 8KB h fp8 dbuf (16 rows x 144B at 0 / 4096)
  __shared__ __attribute__((aligned(16))) unsigned char hl[98304];

  // fp8 B-frags (x16): lane (l4,l15): col = chosen, k = l4*32 + j
  auto pack8 = [&](const float* M, int col)->ivec8{
    ivec8 q;
#pragma unroll
    for (int w = 0; w < 8; ++w){
      const int k0 = l4 * 32 + w * 4;
      int v = __builtin_amdgcn_cvt_pk_fp8_f32(16.f*M[(k0+0)*384 + col], 16.f*M[(k0+1)*384 + col], 0, 0);
      q[w]  = __builtin_amdgcn_cvt_pk_fp8_f32(16.f*M[(k0+2)*384 + col], 16.f*M[(k0+3)*384 + col], v, 1);
    }
    return q;
  };
  const ivec8 Qz = pack8(U, c), Qr = pack8(U, 128 + c), Qh = pack8(U, 256 + c);
  const ivec8 Pz = pack8(W, c), Pr = pack8(W, 128 + c), Ph = pack8(W, 256 + c);

  const float bz = bv[c] + bv[384 + c];
  const float br = bv[128 + c] + bv[384 + 128 + c];
  const float bx = bv[256 + c];
  const float bu = bv[384 + 256 + c];
  const fvec4 ZF  = {0.f,0.f,0.f,0.f};
  const fvec4 CZv = {bz,bz,bz,bz};                   // loop-invariant MFS C-inputs
  const fvec4 CRv = {br,br,br,br};
  const fvec4 CXv = {bx,bx,bx,bx};
  const fvec4 CUv = {bu,bu,bu,bu};                   // recurrent-hh bias via MFMA C

  for (int i = tid; i < 2048; i += 512) ((int*)hl)[i] = 0;   // zero both h buffers
  float h16 = 0.f;                                  // 16*h[batch l4][c] fp32 master

  // x A-frag: tile row l15 = (batch l15>>2, step l15&3)
  const int  brow = l15 >> 2, srow = l15 & 3;
  const long tbx  = (long)(grp * 4 + brow) * TLEN;
  const int  tb0  = dir ? (TLEN - 1) : 0, tsg = dir ? -1 : 1;
  auto tix = [&](int t){ t = (t > TLEN - 1) ? (TLEN - 1) : t; return tb0 + tsg * t; };
  const unsigned char* __restrict__ xb = embq + l4 * 32;     // hoisted per-lane base
#define XLD(tok) (*(const ivec8*)(xb + ((size_t)(tok) << 7)))
#define MFS(A, B, C) __builtin_amdgcn_mfma_scale_f32_16x16x128_f8f6f4(A, B, C, 0, 0, 0, 0x7B7B7B7B, 0, 0x7B7B7B7B)

  // E/O xp accumulator sets
  fvec4 eZ, eR, eX, oZ = ZF, oR = ZF, oX = ZF;
  ivec8 xfa, xfb;
  {
    const int t0 = tokens[tbx + tix(srow)];
    ivec8 xf0 = XLD(t0);
    eZ = MFS(xf0, Pz, CZv); eR = MFS(xf0, Pr, CRv); eX = MFS(xf0, Ph, CXv);
    xfa = XLD(tokens[tbx + tix(4 + srow)]);          // x(group 1)
  }
  int tok2 = tokens[tbx + tix(8 + srow)];            // token(group 2)

  const int hrd = l15 * 144 + l4 * 32;               // h A-frag base (byte)
  const int wb  = (4 * l4) * 144 + c;                // 1-byte h write slot

  ivec8 af = {0,0,0,0,0,0,0,0};                      // stays 0 on non-rdr lanes
  __syncthreads();

  // Step: [pred] ds_read issue -> XTOP (fills read latency) -> rec MFS (aR,aU,aZ)
  // -> gate (r-chain first, z last) -> h byte write -> lgkm drain -> barrier.
#define STEP(S, P, XZ, XR, XX, XTOP) { \
    if (rdr){ \
      *(ivec4*)&af       = *(const ivec4*)&hl[(P) + hrd]; \
      *((ivec4*)&af + 1) = *(const ivec4*)&hl[(P) + hrd + 16]; \
    } \
    XTOP \
    fvec4 aR = MFS(af, Qr, ZF); \
    fvec4 aU = MFS(af, Qh, CUv); \
    fvec4 aZ = MFS(af, Qz, ZF); \
    float eRv = __builtin_amdgcn_exp2f(-1.44269504f * (XR[S] + aR[0])); \
    float r   = __builtin_amdgcn_rcpf(1.f + eRv); \
    float a   = XX[S] + r * aU[0]; a = fmaxf(a, -30.f); \
    float y   = __builtin_amdgcn_exp2f(-2.88539008f * a); \
    float eZv = __builtin_amdgcn_exp2f(-1.44269504f * (XZ[S] + aZ[0])); \
    float z   = __builtin_amdgcn_rcpf(1.f + eZv); \
    float th16 = (16.f - 16.f * y) * __builtin_amdgcn_rcpf(1.f + y); \
    h16 = th16 + z * (h16 - th16); \
    hl[((P) ^ 4096) + wb] = \
        (unsigned char)__builtin_amdgcn_cvt_pk_fp8_f32(h16, h16, 0, 0); \
    asm volatile("s_waitcnt lgkmcnt(0)" ::: "memory"); \
    __builtin_amdgcn_s_barrier(); \
}

  for (int g = 0; g < 128; g += 2){
    // even group g: gates from E; weave O(g+1) from xfa; prefetch xfb <- x(g+2)
    STEP(0, 0,    eZ,eR,eX, { oZ = MFS(xfa, Pz, CZv); })
    STEP(1, 4096, eZ,eR,eX, { oR = MFS(xfa, Pr, CRv);
                              xfb = XLD(tok2); })
    STEP(2, 0,    eZ,eR,eX, { oX = MFS(xfa, Ph, CXv);
                              tok2 = tokens[tbx + tix(4 * (g + 3) + srow)]; })
    STEP(3, 4096, eZ,eR,eX, { })
    // odd group g+1: gates from O; weave E(g+2) from xfb; prefetch xfa <- x(g+3)
    STEP(0, 0,    oZ,oR,oX, { eZ = MFS(xfb, Pz, CZv); })
    STEP(1, 4096, oZ,oR,oX, { eR = MFS(xfb, Pr, CRv);
                              xfa = XLD(tok2); })
    STEP(2, 0,    oZ,oR,oX, { eX = MFS(xfb, Ph, CXv);
                              tok2 = tokens[tbx + tix(4 * (g + 4) + srow)]; })
    STEP(3, 4096, oZ,oR,oX, { })
  }
#undef STEP
#undef MFS
#undef XLD

  // final state -> hbuf[512][256]: every lane owns (batch l4, col c); h = h16/16
  hbuf[(size_t)(grp * 4 + l4) * 256 + dir * 128 + c] = h16 * 0.0625f;
}

// ---------------- head: sigmoid(hcat @ Wd + bd) ----------------
__global__ void head_k(const float* __restrict__ hbuf, const float* __restrict__ Wd,
                       const float* __restrict__ bd, float* __restrict__ out){
  const int wid = threadIdx.x >> 6, lane = threadIdx.x & 63;
  const int b = blockIdx.x * 4 + wid;
  const float* hr = hbuf + (size_t)b * 256;
  float s = 0.f;
#pragma unroll
  for (int j = 0; j < 4; ++j){ const int k = j * 64 + lane; s += hr[k] * Wd[k]; }
#pragma unroll
  for (int off = 32; off > 0; off >>= 1) s += __shfl_down(s, off);
  if (lane == 0) out[b] = 1.f / (1.f + __expf(-(s + bd[0])));
}

extern "C" void kernel_launch(void* const* d_in, const int* in_sizes, int n_in,
                              void* d_out, int out_size, void* d_ws, size_t ws_size,
                              hipStream_t stream){
  const int*   tokens = (const int*)  d_in[0];
  const float* emb    = (const float*)d_in[1];
  const float* Wf     = (const float*)d_in[2];
  const float* Uf     = (const float*)d_in[3];
  const float* bf_    = (const float*)d_in[4];
  const float* Wb     = (const float*)d_in[5];
  const float* Ub     = (const float*)d_in[6];
  const float* bb_    = (const float*)d_in[7];
  const float* Wd     = (const float*)d_in[8];
  const float* bd     = (const float*)d_in[9];
  float* out = (float*)d_out;

  unsigned char* embq = (unsigned char*)d_ws;                        // 6.4 MB fp8 table
  float* hbuf = (float*)((char*)d_ws + (size_t)VOC * HD);            // 512 KB

  const int n4 = VOC * HD / 4;
  emb_cvt8<<<(n4 + 255) / 256, 256, 0, stream>>>(emb, (int*)embq, n4);
  gru_scan<<<256, 512, 0, stream>>>(tokens, embq, Wf, Uf, bf_, Wb, Ub, bb_, hbuf);
  head_k<<<128, 256, 0, stream>>>(hbuf, Wd, bd, out);
}

// Round 17
// 161.423 us; speedup vs baseline: 1.0150x; 1.0150x over previous
//
#include <hip/hip_runtime.h>

#define TLEN 512
#define HD 128
#define VOC 50000

typedef float fvec4 __attribute__((ext_vector_type(4)));   // f32 MFMA accumulator
typedef int   ivec4 __attribute__((ext_vector_type(4)));   // 16B LDS read
typedef int   ivec8 __attribute__((ext_vector_type(8)));   // 32 fp8 = f8f6f4 operand

// ---------------- emb fp32 -> fp8 e4m3 (x16 scale) table ----------------
__global__ void emb_cvt8(const float* __restrict__ emb, int* __restrict__ out, int n4){
  int i = blockIdx.x * blockDim.x + threadIdx.x;
  if (i < n4){
    float4 v = *(const float4*)(emb + (size_t)i * 4);
    int p = __builtin_amdgcn_cvt_pk_fp8_f32(16.f * v.x, 16.f * v.y, 0, 0);
    p     = __builtin_amdgcn_cvt_pk_fp8_f32(16.f * v.z, 16.f * v.w, p, 1);
    out[i] = p;
  }
}

// ---------------- persistent bidirectional GRU scan: 8-wave x 1 col-tile ----------------
// FINAL (r15 verbatim, best verified 161.6us): r16's aR->aU->aZ reorder + C-folds
// REGRESSED (163.8) -- r15's order keeps both sigmoid exp2's early & independent.
// 256 blocks = 256 CUs (96KB LDS pin): 0..127 fwd, 128..255 bwd; 4 batches each
// at A-tile rows {0,4,8,12}; only lanes (l15&3)==0 ds_read their A-frag (rest 0).
// Per wave per step: [pred] 2 ds_read_b128 + 1 woven xp MFS + 3 rec MFS + 1 gate
// + 1-byte h write + 1 barrier. All fp8 stored x16, e8m0 scale 2^-4/side (net 1).
// h master kept as 16*h (exact). r13 lesson: keep the 4-lanes/dword byte writes.
__global__ __launch_bounds__(512, 2) void gru_scan(
    const int* __restrict__ tokens, const unsigned char* __restrict__ embq,
    const float* __restrict__ Wf, const float* __restrict__ Uf, const float* __restrict__ bfv,
    const float* __restrict__ Wb, const float* __restrict__ Ub, const float* __restrict__ bbv,
    float* __restrict__ hbuf)
{
  const int tid  = threadIdx.x;
  const int wid  = tid >> 6, lane = tid & 63;
  const int l15  = lane & 15, l4 = lane >> 4;
  const int dir  = blockIdx.x >> 7, grp = blockIdx.x & 127;
  const int c    = wid * 16 + l15;                   // this lane's single gate column
  const bool rdr = (l15 & 3) == 0;                   // lane supplies a nonzero A row

  const float* __restrict__ W  = dir ? Wb : Wf;
  const float* __restrict__ U  = dir ? Ub : Uf;
  const float* __restrict__ bv = dir ? bbv : bfv;

  // claim 96KB -> 1 block/CU; used: 8KB h fp8 dbuf (16 rows x 144B at 0 / 4096)
  __shared__ __attribute__((aligned(16))) unsigned char hl[98304];

  // fp8 B-frags (x16): lane (l4,l15): col = chosen, k = l4*32 + j
  auto pack8 = [&](const float* M, int col)->ivec8{
    ivec8 q;
#pragma unroll
    for (int w = 0; w < 8; ++w){
      const int k0 = l4 * 32 + w * 4;
      int v = __builtin_amdgcn_cvt_pk_fp8_f32(16.f*M[(k0+0)*384 + col], 16.f*M[(k0+1)*384 + col], 0, 0);
      q[w]  = __builtin_amdgcn_cvt_pk_fp8_f32(16.f*M[(k0+2)*384 + col], 16.f*M[(k0+3)*384 + col], v, 1);
    }
    return q;
  };
  const ivec8 Qz = pack8(U, c), Qr = pack8(U, 128 + c), Qh = pack8(U, 256 + c);
  const ivec8 Pz = pack8(W, c), Pr = pack8(W, 128 + c), Ph = pack8(W, 256 + c);

  const float bz = bv[c] + bv[384 + c];
  const float br = bv[128 + c] + bv[384 + 128 + c];
  const float bx = bv[256 + c];
  const float bu = bv[384 + 256 + c];
  const fvec4 ZF = {0.f,0.f,0.f,0.f};
#define SP4(b) ((fvec4){(b),(b),(b),(b)})

  for (int i = tid; i < 2048; i += 512) ((int*)hl)[i] = 0;   // zero both h buffers
  float h16 = 0.f;                                  // 16*h[batch l4][c] fp32 master

  // x A-frag: tile row l15 = (batch l15>>2, step l15&3)
  const int  brow = l15 >> 2, srow = l15 & 3;
  const long tbx  = (long)(grp * 4 + brow) * TLEN;
  const int  tb0  = dir ? (TLEN - 1) : 0, tsg = dir ? -1 : 1;
  auto tix = [&](int t){ t = (t > TLEN - 1) ? (TLEN - 1) : t; return tb0 + tsg * t; };
  const unsigned char* __restrict__ xb = embq + l4 * 32;     // hoisted per-lane base
#define XLD(tok) (*(const ivec8*)(xb + ((size_t)(tok) << 7)))
#define MFS(A, B, C) __builtin_amdgcn_mfma_scale_f32_16x16x128_f8f6f4(A, B, C, 0, 0, 0, 0x7B7B7B7B, 0, 0x7B7B7B7B)

  // E/O xp accumulator sets
  fvec4 eZ, eR, eX, oZ = ZF, oR = ZF, oX = ZF;
  ivec8 xfa, xfb;
  {
    const int t0 = tokens[tbx + tix(srow)];
    ivec8 xf0 = XLD(t0);
    eZ = MFS(xf0, Pz, SP4(bz)); eR = MFS(xf0, Pr, SP4(br)); eX = MFS(xf0, Ph, SP4(bx));
    xfa = XLD(tokens[tbx + tix(4 + srow)]);          // x(group 1)
  }
  int tok2 = tokens[tbx + tix(8 + srow)];            // token(group 2)

  const int hrd = l15 * 144 + l4 * 32;               // h A-frag base (byte)
  const int wb  = (4 * l4) * 144 + c;                // 1-byte h write slot

  ivec8 af = {0,0,0,0,0,0,0,0};                      // stays 0 on non-rdr lanes
  __syncthreads();

  // Step: [pred] ds_read issue -> XTOP (fills read latency) -> rec MFS (aR,aZ,aU)
  // -> gate (early independent exp2's; z rcp overlaps th16 chain) -> h byte write
  // -> lgkm drain -> barrier.
#define STEP(S, P, XZ, XR, XX, XTOP) { \
    if (rdr){ \
      *(ivec4*)&af       = *(const ivec4*)&hl[(P) + hrd]; \
      *((ivec4*)&af + 1) = *(const ivec4*)&hl[(P) + hrd + 16]; \
    } \
    XTOP \
    fvec4 aR = MFS(af, Qr, ZF); \
    fvec4 aZ = MFS(af, Qz, ZF); \
    fvec4 aU = MFS(af, Qh, ZF); \
    float eRv = __builtin_amdgcn_exp2f(-1.44269504f * (XR[S] + aR[0])); \
    float eZv = __builtin_amdgcn_exp2f(-1.44269504f * (XZ[S] + aZ[0])); \
    float r   = __builtin_amdgcn_rcpf(1.f + eRv); \
    float a   = XX[S] + r * (aU[0] + bu); a = fmaxf(a, -30.f); \
    float y   = __builtin_amdgcn_exp2f(-2.88539008f * a); \
    float z   = __builtin_amdgcn_rcpf(1.f + eZv); \
    float th16 = (16.f - 16.f * y) * __builtin_amdgcn_rcpf(1.f + y); \
    h16 = th16 + z * (h16 - th16); \
    hl[((P) ^ 4096) + wb] = \
        (unsigned char)__builtin_amdgcn_cvt_pk_fp8_f32(h16, h16, 0, 0); \
    asm volatile("s_waitcnt lgkmcnt(0)" ::: "memory"); \
    __builtin_amdgcn_s_barrier(); \
}

  for (int g = 0; g < 128; g += 2){
    // even group g: gates from E; weave O(g+1) from xfa; prefetch xfb <- x(g+2)
    STEP(0, 0,    eZ,eR,eX, { oZ = MFS(xfa, Pz, SP4(bz)); })
    STEP(1, 4096, eZ,eR,eX, { oR = MFS(xfa, Pr, SP4(br));
                              xfb = XLD(tok2); })
    STEP(2, 0,    eZ,eR,eX, { oX = MFS(xfa, Ph, SP4(bx));
                              tok2 = tokens[tbx + tix(4 * (g + 3) + srow)]; })
    STEP(3, 4096, eZ,eR,eX, { })
    // odd group g+1: gates from O; weave E(g+2) from xfb; prefetch xfa <- x(g+3)
    STEP(0, 0,    oZ,oR,oX, { eZ = MFS(xfb, Pz, SP4(bz)); })
    STEP(1, 4096, oZ,oR,oX, { eR = MFS(xfb, Pr, SP4(br));
                              xfa = XLD(tok2); })
    STEP(2, 0,    oZ,oR,oX, { eX = MFS(xfb, Ph, SP4(bx));
                              tok2 = tokens[tbx + tix(4 * (g + 4) + srow)]; })
    STEP(3, 4096, oZ,oR,oX, { })
  }
#undef STEP
#undef MFS
#undef XLD
#undef SP4

  // final state -> hbuf[512][256]: every lane owns (batch l4, col c); h = h16/16
  hbuf[(size_t)(grp * 4 + l4) * 256 + dir * 128 + c] = h16 * 0.0625f;
}

// ---------------- head: sigmoid(hcat @ Wd + bd) ----------------
__global__ void head_k(const float* __restrict__ hbuf, const float* __restrict__ Wd,
                       const float* __restrict__ bd, float* __restrict__ out){
  const int wid = threadIdx.x >> 6, lane = threadIdx.x & 63;
  const int b = blockIdx.x * 4 + wid;
  const float* hr = hbuf + (size_t)b * 256;
  float s = 0.f;
#pragma unroll
  for (int j = 0; j < 4; ++j){ const int k = j * 64 + lane; s += hr[k] * Wd[k]; }
#pragma unroll
  for (int off = 32; off > 0; off >>= 1) s += __shfl_down(s, off);
  if (lane == 0) out[b] = 1.f / (1.f + __expf(-(s + bd[0])));
}

extern "C" void kernel_launch(void* const* d_in, const int* in_sizes, int n_in,
                              void* d_out, int out_size, void* d_ws, size_t ws_size,
                              hipStream_t stream){
  const int*   tokens = (const int*)  d_in[0];
  const float* emb    = (const float*)d_in[1];
  const float* Wf     = (const float*)d_in[2];
  const float* Uf     = (const float*)d_in[3];
  const float* bf_    = (const float*)d_in[4];
  const float* Wb     = (const float*)d_in[5];
  const float* Ub     = (const float*)d_in[6];
  const float* bb_    = (const float*)d_in[7];
  const float* Wd     = (const float*)d_in[8];
  const float* bd     = (const float*)d_in[9];
  float* out = (float*)d_out;

  unsigned char* embq = (unsigned char*)d_ws;                        // 6.4 MB fp8 table
  float* hbuf = (float*)((char*)d_ws + (size_t)VOC * HD);            // 512 KB

  const int n4 = VOC * HD / 4;
  emb_cvt8<<<(n4 + 255) / 256, 256, 0, stream>>>(emb, (int*)embq, n4);
  gru_scan<<<256, 512, 0, stream>>>(tokens, embq, Wf, Uf, bf_, Wb, Ub, bb_, hbuf);
  head_k<<<128, 256, 0, stream>>>(hbuf, Wd, bd, out);
}